// Round 9
// baseline (44.896 us; speedup 1.0000x reference)
//
#include <hip/hip_runtime.h>

// Separable QP projection: hybrid bisection + Illinois false-position.
// One 256-thread block per row (B=4096, N=4096), 16 elems/thread.
//
// R6-R8 post-mortem: the amdgpu allocator refuses VGPR residency for the
// per-element state (VGPR stuck at ~52 through launch_bounds, waves_per_eu,
// and asm pins) and remats it from L1/L2 every probe (~1.7us/sum). Fix:
// EXPLICIT LDS residency of a transformed 3-array state:
//   clip(z + lam*ia, m, M) - z == ia * med3(lam, lb, hb),
//   lb = 2g*(m-z), hb = 2g*(M-z), ia = 1/(2g)   (the breakpoints).
// Loop body: 2 VALU/elem (med3+fma) + 12 conflict-free ds_read_b128.
// Also: lo = min(lb), hi = max(hb); sums compare Sum(x-z) vs xi - Sum(z);
// epilogue x = m + ia*(med3(lam,lb,hb) - lb)  (exact at clamps, no z reread).
// LDS 48KB/block -> 3 blocks/CU (144KB of 160KB), 12 waves/CU.

#define BISECT_STEPS 6
#define TOTAL_STEPS  9   // 6 bisection + 3 Illinois

// ---- DPP wave64 reduction helpers (gfx9-family row ops) ----
template<int CTRL, int RM>
__device__ __forceinline__ float dpp_add(float v) {
    int t = __builtin_amdgcn_update_dpp(0, __float_as_int(v), CTRL, RM, 0xf, false);
    return v + __int_as_float(t);
}
template<int CTRL, int RM>
__device__ __forceinline__ float dpp_min(float v) {
    int t = __builtin_amdgcn_update_dpp(0x7f800000, __float_as_int(v), CTRL, RM, 0xf, false);
    return fminf(v, __int_as_float(t));
}
template<int CTRL, int RM>
__device__ __forceinline__ float dpp_max(float v) {
    int t = __builtin_amdgcn_update_dpp(0xff800000, __float_as_int(v), CTRL, RM, 0xf, false);
    return fmaxf(v, __int_as_float(t));
}

__device__ __forceinline__ float wave_sum(float v) {
    v = dpp_add<0x111, 0xf>(v);   // row_shr:1
    v = dpp_add<0x112, 0xf>(v);   // row_shr:2
    v = dpp_add<0x114, 0xf>(v);   // row_shr:4
    v = dpp_add<0x118, 0xf>(v);   // row_shr:8
    v = dpp_add<0x142, 0xa>(v);   // row_bcast:15
    v = dpp_add<0x143, 0xc>(v);   // row_bcast:31
    return __int_as_float(__builtin_amdgcn_readlane(__float_as_int(v), 63));
}
__device__ __forceinline__ float wave_min(float v) {
    v = dpp_min<0x111, 0xf>(v);
    v = dpp_min<0x112, 0xf>(v);
    v = dpp_min<0x114, 0xf>(v);
    v = dpp_min<0x118, 0xf>(v);
    v = dpp_min<0x142, 0xa>(v);
    v = dpp_min<0x143, 0xc>(v);
    return __int_as_float(__builtin_amdgcn_readlane(__float_as_int(v), 63));
}
__device__ __forceinline__ float wave_max(float v) {
    v = dpp_max<0x111, 0xf>(v);
    v = dpp_max<0x112, 0xf>(v);
    v = dpp_max<0x114, 0xf>(v);
    v = dpp_max<0x118, 0xf>(v);
    v = dpp_max<0x142, 0xa>(v);
    v = dpp_max<0x143, 0xc>(v);
    return __int_as_float(__builtin_amdgcn_readlane(__float_as_int(v), 63));
}

__global__ __launch_bounds__(256) void qp_proj_n4096(
    const float* __restrict__ z,
    const float* __restrict__ gamma,
    const float* __restrict__ mlo,
    const float* __restrict__ mhi,
    const float* __restrict__ xi,
    float* __restrict__ out)
{
    constexpr int N = 4096;
    const int row  = blockIdx.x;
    const int tid  = threadIdx.x;     // 0..255
    const int lane = tid & 63;
    const int wid  = tid >> 6;        // 0..3

    const float4* zrow = reinterpret_cast<const float4*>(z + (size_t)row * N);
    const float4* g4   = reinterpret_cast<const float4*>(gamma);
    const float4* m4   = reinterpret_cast<const float4*>(mlo);
    const float4* M4   = reinterpret_cast<const float4*>(mhi);
    float4*       orow = reinterpret_cast<float4*>(out + (size_t)row * N);

    // Explicit per-block state store. [chunk][tid] float4: consecutive lanes
    // read contiguous 16B -> conflict-free ds_read/write_b128.
    __shared__ float4 LB[4][256];     // breakpoints lb = 2g*(m - z)
    __shared__ float4 HB[4][256];     // breakpoints hb = 2g*(M - z)
    __shared__ float4 IA[4][256];     // ia = 1/(2g)
    __shared__ float  wred[5][4];     // prologue partials: min,max,sum_m,sum_M,sum_z
    __shared__ float  wsum[2][4];     // double-buffered: one barrier per iter

    float pmin =  INFINITY;   // min lb  (= lam_low)
    float pmax = -INFINITY;   // max hb  (= lam_high)
    float psm  = 0.0f;        // sum m   (g(lo) = sum m - xi)
    float psM  = 0.0f;        // sum M   (g(hi) = sum M - xi)
    float psz  = 0.0f;        // sum z   (loop compares Sum(x-z) vs xi - sum z)

    #pragma unroll
    for (int k = 0; k < 4; ++k) {
        const int idx = tid + k * 256;           // float4 index, coalesced
        const float4 zz = zrow[idx];
        const float4 gg = g4[idx];
        const float4 mm = m4[idx];
        const float4 MM = M4[idx];

        const float zs[4] = {zz.x, zz.y, zz.z, zz.w};
        const float gs[4] = {gg.x, gg.y, gg.z, gg.w};
        const float ms[4] = {mm.x, mm.y, mm.z, mm.w};
        const float Ms[4] = {MM.x, MM.y, MM.z, MM.w};

        float lb[4], hb[4], ia[4];
        #pragma unroll
        for (int c = 0; c < 4; ++c) {
            const float tg = 2.0f * gs[c];
            lb[c] = tg * (ms[c] - zs[c]);
            hb[c] = tg * (Ms[c] - zs[c]);
            ia[c] = 1.0f / tg;
            pmin = fminf(pmin, lb[c]);
            pmax = fmaxf(pmax, hb[c]);
            psm += ms[c];
            psM += Ms[c];
            psz += zs[c];
        }
        LB[k][tid] = make_float4(lb[0], lb[1], lb[2], lb[3]);
        HB[k][tid] = make_float4(hb[0], hb[1], hb[2], hb[3]);
        IA[k][tid] = make_float4(ia[0], ia[1], ia[2], ia[3]);
    }

    // ---- block reduce the 5 prologue quantities (one barrier) ----
    pmin = wave_min(pmin);
    pmax = wave_max(pmax);
    psm  = wave_sum(psm);
    psM  = wave_sum(psM);
    psz  = wave_sum(psz);
    if (lane == 0) {
        wred[0][wid] = pmin; wred[1][wid] = pmax;
        wred[2][wid] = psm;  wred[3][wid] = psM;  wred[4][wid] = psz;
    }
    __syncthreads();
    float lo = fminf(fminf(wred[0][0], wred[0][1]), fminf(wred[0][2], wred[0][3]));
    float hi = fmaxf(fmaxf(wred[1][0], wred[1][1]), fmaxf(wred[1][2], wred[1][3]));
    const float smT = (wred[2][0] + wred[2][1]) + (wred[2][2] + wred[2][3]);
    const float sMT = (wred[3][0] + wred[3][1]) + (wred[3][2] + wred[3][3]);
    const float szT = (wred[4][0] + wred[4][1]) + (wred[4][2] + wred[4][3]);

    const float xir     = xi[row];
    const float xir_eff = xir - szT;          // loop: Sum(x - z) - xir_eff
    float glo = smT - xir;                    // <= 0 at lo
    float ghi = sMT - xir;                    // >= 0 at hi
    int side = 0;

    // ---- 6 bisection + 3 Illinois steps, each ONE sum ----
    for (int it = 0; it < TOTAL_STEPS; ++it) {
        const float w = hi - lo;
        float cand;
        if (it < BISECT_STEPS) {
            cand = fmaf(0.5f, w, lo);
        } else {
            const float denom = ghi - glo;           // > 0 (bracket invariant)
            cand = (lo * ghi - hi * glo) / denom;    // false-position point
            cand = fminf(fmaxf(cand, fmaf(0.0625f, w, lo)),
                         fmaf(-0.0625f, w, hi));     // strictly interior
        }

        // eval: 2 VALU/elem from LDS (med3 + fma), 12 ds_read_b128
        float t0 = 0.f, t1 = 0.f, t2 = 0.f, t3 = 0.f;
        #pragma unroll
        for (int k = 0; k < 4; ++k) {
            const float4 lb = LB[k][tid];
            const float4 hb = HB[k][tid];
            const float4 ia = IA[k][tid];
            t0 = fmaf(ia.x, __builtin_amdgcn_fmed3f(cand, lb.x, hb.x), t0);
            t1 = fmaf(ia.y, __builtin_amdgcn_fmed3f(cand, lb.y, hb.y), t1);
            t2 = fmaf(ia.z, __builtin_amdgcn_fmed3f(cand, lb.z, hb.z), t2);
            t3 = fmaf(ia.w, __builtin_amdgcn_fmed3f(cand, lb.w, hb.w), t3);
        }
        const float sw = wave_sum((t0 + t1) + (t2 + t3));

        const int p = it & 1;
        if (lane == 0) wsum[p][wid] = sw;
        __syncthreads();
        // iter it's write to buf p is protected from iter it-2's reads by
        // the barrier at iter it-1 -> single barrier suffices.
        const float s = ((wsum[p][0] + wsum[p][1]) + (wsum[p][2] + wsum[p][3]))
                        - xir_eff;            // == Sum(x) - xi (up to rounding)

        if (s > 0.0f) {                 // root below cand
            hi = cand;
            if (side == 1) glo *= 0.5f; // Illinois stale-endpoint halving
            ghi = s;
            side = 1;
        } else {
            lo = cand;
            if (side == -1) ghi *= 0.5f;
            glo = s;
            side = -1;
        }
    }

    // final lambda: interpolated root of last bracket (piecewise-linear g),
    // clamped into [lo,hi]; midpoint fallback if degenerate.
    const float denom = ghi - glo;
    float lam = (denom > 0.0f) ? (lo * ghi - hi * glo) / denom
                               : fmaf(0.5f, hi - lo, lo);
    lam = fminf(fmaxf(lam, lo), hi);

    // ---- final x = m + ia*(med3(lam, lb, hb) - lb) ----
    // exact m/M at the clamps; interior = z + lam*ia up to ~1e-7.
    #pragma unroll
    for (int k = 0; k < 4; ++k) {
        const int idx = tid + k * 256;
        const float4 mm = m4[idx];               // shared (N,) vector, L1-hot
        const float4 lb = LB[k][tid];
        const float4 hb = HB[k][tid];
        const float4 ia = IA[k][tid];
        float4 r;
        r.x = fmaf(ia.x, __builtin_amdgcn_fmed3f(lam, lb.x, hb.x) - lb.x, mm.x);
        r.y = fmaf(ia.y, __builtin_amdgcn_fmed3f(lam, lb.y, hb.y) - lb.y, mm.y);
        r.z = fmaf(ia.z, __builtin_amdgcn_fmed3f(lam, lb.z, hb.z) - lb.z, mm.z);
        r.w = fmaf(ia.w, __builtin_amdgcn_fmed3f(lam, lb.w, hb.w) - lb.w, mm.w);
        orow[idx] = r;
    }
}

extern "C" void kernel_launch(void* const* d_in, const int* in_sizes, int n_in,
                              void* d_out, int out_size, void* d_ws, size_t ws_size,
                              hipStream_t stream) {
    const float* z     = (const float*)d_in[0];
    const float* gamma = (const float*)d_in[1];
    const float* m     = (const float*)d_in[2];
    const float* M     = (const float*)d_in[3];
    const float* xi    = (const float*)d_in[4];
    float* out = (float*)d_out;

    const int B = in_sizes[4];   // rows (xi has one entry per row)
    // Kernel is specialized to N == 4096 (16 elements / thread, 256 threads).
    qp_proj_n4096<<<dim3(B), dim3(256), 0, stream>>>(z, gamma, m, M, xi, out);
}